// Round 1
// baseline (139.504 us; speedup 1.0000x reference)
//
#include <hip/hip_runtime.h>

typedef __attribute__((ext_vector_type(8))) short short8;
typedef __attribute__((ext_vector_type(4))) float f32x4;

// round-to-nearest-even f32 -> bf16 (bit manipulation; avoids API variance)
__device__ inline unsigned short f2bf(float f) {
    unsigned u = __float_as_uint(f);
    u += 0x7FFFu + ((u >> 16) & 1u);
    return (unsigned short)(u >> 16);
}

#define BM 128
#define BN 128
#define BK 32
#define NT 256

// C[m][n] = sum_k X[m][k] * W[n][k]   (B-transposed GEMM, bf16 MFMA)
// X: [Mpad x K] f32 (x flattened; last 64 rows are t=127 "garbage", overwritten later)
// W: [N x K] f32
// C: [Mpad x N] f32  (= d_out; slot t occupies rows t*64..t*64+63)
__global__ __launch_bounds__(NT, 2) void eventprop_gemm_kernel(
    const float* __restrict__ X, const float* __restrict__ W, float* __restrict__ C,
    const int K, const int N, const int nbn)
{
    __shared__ unsigned short As[BM][BK];   // 8 KB
    __shared__ unsigned short Bs[BN][BK];   // 8 KB

    const int bid = blockIdx.x;
    const int bm = bid / nbn, bn = bid % nbn;
    const int m0 = bm * BM, n0 = bn * BN;
    const int tid = threadIdx.x;
    const int lane = tid & 63;
    const int wave = tid >> 6;
    const int wr = wave >> 1, wc = wave & 1;   // 2x2 waves, each owns 64x64
    const int lrow = lane & 15, kg = lane >> 4; // fragment row, k-group

    f32x4 acc[4][4] = {};

    for (int kt = 0; kt < K; kt += BK) {
        // ---- stage A-tile and B-tile (128x32 f32 each) -> bf16 LDS ----
        #pragma unroll
        for (int p = 0; p < 4; ++p) {
            const int idx = p * NT + tid;        // float4 index 0..1023
            const int row = idx >> 3;            // 8 float4 per row
            const int c4  = (idx & 7) * 4;
            const float4 fa = *(const float4*)&X[(size_t)(m0 + row) * K + kt + c4];
            ushort4 ua;
            ua.x = f2bf(fa.x); ua.y = f2bf(fa.y); ua.z = f2bf(fa.z); ua.w = f2bf(fa.w);
            *(ushort4*)&As[row][c4] = ua;
            const float4 fb = *(const float4*)&W[(size_t)(n0 + row) * K + kt + c4];
            ushort4 ub;
            ub.x = f2bf(fb.x); ub.y = f2bf(fb.y); ub.z = f2bf(fb.z); ub.w = f2bf(fb.w);
            *(ushort4*)&Bs[row][c4] = ub;
        }
        __syncthreads();

        // ---- fragments + MFMA ----
        short8 a[4], b[4];
        #pragma unroll
        for (int mi = 0; mi < 4; ++mi)
            a[mi] = *(const short8*)&As[wr * 64 + mi * 16 + lrow][kg * 8];
        #pragma unroll
        for (int ni = 0; ni < 4; ++ni)
            b[ni] = *(const short8*)&Bs[wc * 64 + ni * 16 + lrow][kg * 8];
        #pragma unroll
        for (int mi = 0; mi < 4; ++mi)
            #pragma unroll
            for (int ni = 0; ni < 4; ++ni)
                acc[mi][ni] = __builtin_amdgcn_mfma_f32_16x16x32_bf16(
                    a[mi], b[ni], acc[mi][ni], 0, 0, 0);
        __syncthreads();
    }

    // ---- epilogue: C/D layout col=lane&15, row=(lane>>4)*4+reg  [m89-verified] ----
    const int r0 = kg * 4;
    #pragma unroll
    for (int mi = 0; mi < 4; ++mi) {
        #pragma unroll
        for (int ni = 0; ni < 4; ++ni) {
            #pragma unroll
            for (int r = 0; r < 4; ++r) {
                const int row = m0 + wr * 64 + mi * 16 + r0 + r;
                const int col = n0 + wc * 64 + ni * 16 + lrow;
                C[(size_t)row * N + col] = acc[mi][ni][r];
            }
        }
    }
}

// In-place scan over T on d_out. Thread owns one (b,o) column.
// Recurrence (AM=0.9, BM=0.1, AS=0):
//   Vn = 0.9*V + 0.1*I ; s = Vn>1 ; V = (1-s)*Vn ; I = cur[i]
//   out[i+1] = s ; out[0] = 0
// In-place safe: slot i+1 is read (prefetch) before it is written, same thread.
__global__ void eventprop_scan_kernel(float* __restrict__ out, const int BO, const int T)
{
    const int idx = blockIdx.x * blockDim.x + threadIdx.x;  // 0..BO-1
    float V = 0.f, I = 0.f;
    float c = out[idx];          // cur[0] (slot 0)
    out[idx] = 0.f;              // out[0] = 0
    for (int i = 0; i < T - 1; ++i) {
        const float cn = out[(size_t)(i + 1) * BO + idx];   // prefetch cur[i+1] BEFORE store
        const float Vn = 0.9f * V + 0.1f * I;
        const float s = (Vn > 1.0f) ? 1.0f : 0.0f;
        I = c;
        V = (1.0f - s) * Vn;
        out[(size_t)(i + 1) * BO + idx] = s;
        c = cn;
    }
}

extern "C" void kernel_launch(void* const* d_in, const int* in_sizes, int n_in,
                              void* d_out, int out_size, void* d_ws, size_t ws_size,
                              hipStream_t stream) {
    const float* x = (const float*)d_in[0];   // [T, B, IN] f32
    const float* w = (const float*)d_in[1];   // [OUT, IN] f32
    float* out = (float*)d_out;               // [T, B, OUT] f32

    const int T = 128, B = 64, IN = 1024, OUT = 1024;
    const int Mpad = T * B;                   // 8192 rows (incl. 64 garbage rows -> slot 127)
    const int nbn = OUT / BN;                 // 8
    const int nblocks = (Mpad / BM) * nbn;    // 64*8 = 512

    eventprop_gemm_kernel<<<dim3(nblocks), dim3(NT), 0, stream>>>(x, w, out, IN, OUT, nbn);
    eventprop_scan_kernel<<<dim3((B * OUT) / 256), dim3(256), 0, stream>>>(out, B * OUT, T);
}

// Round 2
// 75.614 us; speedup vs baseline: 1.8450x; 1.8450x over previous
//
#include <hip/hip_runtime.h>

typedef __attribute__((ext_vector_type(8))) short short8;
typedef __attribute__((ext_vector_type(4))) float f32x4;

// round-to-nearest-even f32 -> bf16
__device__ __forceinline__ unsigned short f2bf(float f) {
    unsigned u = __float_as_uint(f);
    u += 0x7FFFu + ((u >> 16) & 1u);
    return (unsigned short)(u >> 16);
}

// ---------------------------------------------------------------------------
// Prepass: convert x [Mpad*K] f32 and w [N*K] f32 to bf16 in workspace.
// Each thread converts 8 elements (32B read, 16B write).
// ---------------------------------------------------------------------------
__global__ void eventprop_cvt_kernel(const float* __restrict__ x, const float* __restrict__ w,
                                     unsigned short* __restrict__ xb, unsigned short* __restrict__ wb,
                                     const int nx, const int ntot)
{
    const int i = blockIdx.x * blockDim.x + threadIdx.x;
    const int e0 = i * 8;
    if (e0 >= ntot) return;
    const float* src;
    unsigned short* dst;
    if (e0 < nx) { src = x + e0; dst = xb + e0; }
    else         { src = w + (e0 - nx); dst = wb + (e0 - nx); }
    const float4 f0 = *(const float4*)(src);
    const float4 f1 = *(const float4*)(src + 4);
    short8 v;
    v[0] = (short)f2bf(f0.x); v[1] = (short)f2bf(f0.y);
    v[2] = (short)f2bf(f0.z); v[3] = (short)f2bf(f0.w);
    v[4] = (short)f2bf(f1.x); v[5] = (short)f2bf(f1.y);
    v[6] = (short)f2bf(f1.z); v[7] = (short)f2bf(f1.w);
    *(short8*)dst = v;
}

// ---------------------------------------------------------------------------
// m97-structure GEMM: C[m][n] = sum_k Xb[m][k]*Wb[n][k], bf16 in, f32 out.
// 128x128 tile, BK=64, 4 waves (2x2), global_load_lds width-16 staging.
// LDS linear [row][64] bf16 (row stride 128B) — matches wave-uniform-base
// + lane*16 destination rule (m104).
// ---------------------------------------------------------------------------
__global__ __launch_bounds__(256, 2) void eventprop_gemm_bf16_kernel(
    const unsigned short* __restrict__ Xb, const unsigned short* __restrict__ Wb,
    float* __restrict__ C, const int K, const int N, const int nbn)
{
    __shared__ unsigned short As[128 * 64];   // 16 KB
    __shared__ unsigned short Bs[128 * 64];   // 16 KB

    const int bid = blockIdx.x;
    const int bm = bid / nbn, bn = bid % nbn;
    const int m0 = bm * 128, n0 = bn * 128;
    const int tid = threadIdx.x;
    const int lane = tid & 63;
    const int wave = tid >> 6;
    const int wr = wave >> 1, wc = wave & 1;     // 2x2 waves, 64x64 each
    const int lrow = lane & 15, kg = lane >> 4;  // MFMA fragment row / k-group
    const int srow = lane >> 3;                  // staging: row within 8-row group
    const int scol = (lane & 7) * 8;             // staging: element col

    f32x4 acc[4][4] = {};

    for (int kt = 0; kt < K; kt += 64) {
        // ---- stage A+B tiles: 16 wave-issues each of 1KB; wave handles 4 ----
        #pragma unroll
        for (int jj = 0; jj < 4; ++jj) {
            const int j = wave * 4 + jj;              // wave-uniform
            const int row = j * 8 + srow;
            const unsigned short* ga = &Xb[(size_t)(m0 + row) * K + kt + scol];
            __builtin_amdgcn_global_load_lds(
                (const __attribute__((address_space(1))) unsigned int*)ga,
                (__attribute__((address_space(3))) unsigned int*)&As[j * 512], 16, 0, 0);
            const unsigned short* gb = &Wb[(size_t)(n0 + row) * K + kt + scol];
            __builtin_amdgcn_global_load_lds(
                (const __attribute__((address_space(1))) unsigned int*)gb,
                (__attribute__((address_space(3))) unsigned int*)&Bs[j * 512], 16, 0, 0);
        }
        __syncthreads();   // compiler drains vmcnt(0) here

        // ---- fragments + MFMA: 2 k-slices of 32 ----
        short8 a[2][4], b[2][4];
        #pragma unroll
        for (int ks = 0; ks < 2; ++ks) {
            #pragma unroll
            for (int mi = 0; mi < 4; ++mi)
                a[ks][mi] = *(const short8*)&As[(wr * 64 + mi * 16 + lrow) * 64 + ks * 32 + kg * 8];
            #pragma unroll
            for (int ni = 0; ni < 4; ++ni)
                b[ks][ni] = *(const short8*)&Bs[(wc * 64 + ni * 16 + lrow) * 64 + ks * 32 + kg * 8];
        }
        #pragma unroll
        for (int ks = 0; ks < 2; ++ks)
            #pragma unroll
            for (int mi = 0; mi < 4; ++mi)
                #pragma unroll
                for (int ni = 0; ni < 4; ++ni)
                    acc[mi][ni] = __builtin_amdgcn_mfma_f32_16x16x32_bf16(
                        a[ks][mi], b[ks][ni], acc[mi][ni], 0, 0, 0);
        __syncthreads();
    }

    // ---- epilogue: C/D layout col=lane&15, row=(lane>>4)*4+reg [m89] ----
    const int r0 = kg * 4;
    #pragma unroll
    for (int mi = 0; mi < 4; ++mi) {
        #pragma unroll
        for (int ni = 0; ni < 4; ++ni) {
            #pragma unroll
            for (int r = 0; r < 4; ++r) {
                const int row = m0 + wr * 64 + mi * 16 + r0 + r;
                const int col = n0 + wc * 64 + ni * 16 + lrow;
                C[(size_t)row * N + col] = acc[mi][ni][r];
            }
        }
    }
}

// ---------------------------------------------------------------------------
// Fallback GEMM (round-1, inline f32->bf16) if ws is too small.
// ---------------------------------------------------------------------------
__global__ __launch_bounds__(256, 2) void eventprop_gemm_f32in_kernel(
    const float* __restrict__ X, const float* __restrict__ W, float* __restrict__ C,
    const int K, const int N, const int nbn)
{
    __shared__ unsigned short As[128][32];
    __shared__ unsigned short Bs[128][32];
    const int bid = blockIdx.x;
    const int bm = bid / nbn, bn = bid % nbn;
    const int m0 = bm * 128, n0 = bn * 128;
    const int tid = threadIdx.x;
    const int lane = tid & 63;
    const int wave = tid >> 6;
    const int wr = wave >> 1, wc = wave & 1;
    const int lrow = lane & 15, kg = lane >> 4;

    f32x4 acc[4][4] = {};
    for (int kt = 0; kt < K; kt += 32) {
        #pragma unroll
        for (int p = 0; p < 4; ++p) {
            const int idx = p * 256 + tid;
            const int row = idx >> 3;
            const int c4  = (idx & 7) * 4;
            const float4 fa = *(const float4*)&X[(size_t)(m0 + row) * K + kt + c4];
            ushort4 ua; ua.x = f2bf(fa.x); ua.y = f2bf(fa.y); ua.z = f2bf(fa.z); ua.w = f2bf(fa.w);
            *(ushort4*)&As[row][c4] = ua;
            const float4 fb = *(const float4*)&W[(size_t)(n0 + row) * K + kt + c4];
            ushort4 ub; ub.x = f2bf(fb.x); ub.y = f2bf(fb.y); ub.z = f2bf(fb.z); ub.w = f2bf(fb.w);
            *(ushort4*)&Bs[row][c4] = ub;
        }
        __syncthreads();
        short8 a[4], b[4];
        #pragma unroll
        for (int mi = 0; mi < 4; ++mi) a[mi] = *(const short8*)&As[wr * 64 + mi * 16 + lrow][kg * 8];
        #pragma unroll
        for (int ni = 0; ni < 4; ++ni) b[ni] = *(const short8*)&Bs[wc * 64 + ni * 16 + lrow][kg * 8];
        #pragma unroll
        for (int mi = 0; mi < 4; ++mi)
            #pragma unroll
            for (int ni = 0; ni < 4; ++ni)
                acc[mi][ni] = __builtin_amdgcn_mfma_f32_16x16x32_bf16(a[mi], b[ni], acc[mi][ni], 0, 0, 0);
        __syncthreads();
    }
    const int r0 = kg * 4;
    #pragma unroll
    for (int mi = 0; mi < 4; ++mi)
        #pragma unroll
        for (int ni = 0; ni < 4; ++ni)
            #pragma unroll
            for (int r = 0; r < 4; ++r)
                C[(size_t)(m0 + wr * 64 + mi * 16 + r0 + r) * N + (n0 + wc * 64 + ni * 16 + lrow)] = acc[mi][ni][r];
}

// ---------------------------------------------------------------------------
// In-place scan over T on d_out (AS = 0 so I_{t+1} = cur[t]).
// ---------------------------------------------------------------------------
__global__ void eventprop_scan_kernel(float* __restrict__ out, const int BO, const int T)
{
    const int idx = blockIdx.x * blockDim.x + threadIdx.x;
    float V = 0.f, I = 0.f;
    float c = out[idx];
    out[idx] = 0.f;
    for (int i = 0; i < T - 1; ++i) {
        const float cn = out[(size_t)(i + 1) * BO + idx];  // prefetch before overwrite
        const float Vn = 0.9f * V + 0.1f * I;
        const float s = (Vn > 1.0f) ? 1.0f : 0.0f;
        I = c;
        V = (1.0f - s) * Vn;
        out[(size_t)(i + 1) * BO + idx] = s;
        c = cn;
    }
}

extern "C" void kernel_launch(void* const* d_in, const int* in_sizes, int n_in,
                              void* d_out, int out_size, void* d_ws, size_t ws_size,
                              hipStream_t stream) {
    const float* x = (const float*)d_in[0];   // [T, B, IN] f32
    const float* w = (const float*)d_in[1];   // [OUT, IN] f32
    float* out = (float*)d_out;               // [T, B, OUT] f32

    const int T = 128, B = 64, IN = 1024, OUT = 1024;
    const int Mpad = T * B;                   // 8192
    const int nbn = OUT / 128;                // 8
    const int nblocks = (Mpad / 128) * nbn;   // 512

    const size_t nx = (size_t)Mpad * IN;      // 8388608
    const size_t nw = (size_t)OUT * IN;       // 1048576
    const size_t need = (nx + nw) * sizeof(unsigned short);  // 18.9 MB

    if (ws_size >= need) {
        unsigned short* xb = (unsigned short*)d_ws;
        unsigned short* wb = xb + nx;
        const int ntot = (int)(nx + nw);
        const int cvt_blocks = (ntot / 8 + 255) / 256;  // 4608
        eventprop_cvt_kernel<<<dim3(cvt_blocks), dim3(256), 0, stream>>>(x, w, xb, wb, (int)nx, ntot);
        eventprop_gemm_bf16_kernel<<<dim3(nblocks), dim3(256), 0, stream>>>(xb, wb, out, IN, OUT, nbn);
    } else {
        eventprop_gemm_f32in_kernel<<<dim3(nblocks), dim3(256), 0, stream>>>(x, w, out, IN, OUT, nbn);
    }
    eventprop_scan_kernel<<<dim3((B * OUT) / 256), dim3(256), 0, stream>>>(out, B * OUT, T);
}